// Round 1
// baseline (170.198 us; speedup 1.0000x reference)
//
#include <hip/hip_runtime.h>

// SSIM fused, v10: occupancy attack. v9 post-mortem: MfmaUtil 5%, VALUBusy 20%,
// Occupancy 32% -> everything stalled; VGPR_Count=64 proves the compiler sank
// v9's "all loads upfront" window (needs ~96 VGPR), so the software pipeline
// never existed in the emitted code. v10 bets on TLP instead of per-wave ILP:
//   - Ring-buffer H planes (32 rows live, not 48): write rt0->slot0, rt1->slot1,
//     v-pass t2=0 (rows 0-31), rt2->slot0, v-pass t2=1 (rows 16-47).
//     Per-wave LDS 7168 -> 5120 B; block 28672 -> 20480 B = EXACTLY 8 blocks/CU
//     (32 waves, 100% occupancy cap; was 5 blocks / 62.5%).
//   - One 16-col tile per wave (grid 8x16x48 = 6144 blocks): halves the serial
//     chain and the register window (12 float4 = 48 VGPR) so waves fit the
//     64-VGPR budget 8 waves/SIMD needs. __launch_bounds__(256, 8).
//   - H pitch = 40 shorts (80 B): b128-aligned; wave b128 reads are perfectly
//     bank-balanced (each bank gets exactly 8 of 256 dwords).
//   - Per-BLOCK partial via LDS pad slots (+1 end barrier): ws stays 24 KB.
// Same math as v9 (harness-verified): band[j]=g[quad*8+j-lm-3] via __shfl,
// h-pass mfma(A,band), v-pass mfma(band,hf), SSIM in packed f32.

#define IMG 512
#define NPIX (16LL * 3 * 512 * 512)
#define GX 8                  /* 512 / (16 cols * 4 waves) */
#define GY 16                 /* 512 / 32 rows */
#define NBLK (GX * GY * 48)   /* 6144 blocks */
#define NPART NBLK            /* one float per block: 24 KB */

typedef short v8s __attribute__((ext_vector_type(8)));   // 8 x bf16 (4 VGPRs)
typedef float v4f __attribute__((ext_vector_type(4)));   // MFMA accumulator
typedef __bf16 bf2 __attribute__((ext_vector_type(2)));
typedef float f2  __attribute__((ext_vector_type(2)));

static __device__ __forceinline__ int cvtpk2(f2 v) {     // v_cvt_pk_bf16_f32
    bf2 r = __builtin_convertvector(v, bf2);
    return __builtin_bit_cast(int, r);
}
static __device__ __forceinline__ unsigned f2bf(float f) {
    unsigned u = __float_as_uint(f);
    return (u + 0x7FFFu + ((u >> 16) & 1u)) >> 16;
}

// One row-tile of raw loads: 4 float4 (rows grow, cols gcol..gcol+7, 2 imgs).
template <bool EDGE>
static __device__ __forceinline__ void load_rt(
    const float* __restrict__ p1, const float* __restrict__ p2,
    int grow, int gcol,
    float4& a0, float4& a1, float4& b0, float4& b1)
{
    if (!EDGE) {
        const float* r1 = p1 + (size_t)grow * IMG + gcol;
        const float* r2 = p2 + (size_t)grow * IMG + gcol;
        a0 = *(const float4*)r1;       a1 = *(const float4*)(r1 + 4);
        b0 = *(const float4*)r2;       b1 = *(const float4*)(r2 + 4);
    } else {
        float4 z4; z4.x = z4.y = z4.z = z4.w = 0.f;
        a0 = a1 = b0 = b1 = z4;
        if ((unsigned)grow < IMG) {
            const float* r1 = p1 + (size_t)grow * IMG;
            const float* r2 = p2 + (size_t)grow * IMG;
            if ((unsigned)gcol < IMG) {
                a0 = *(const float4*)(r1 + gcol);
                b0 = *(const float4*)(r2 + gcol);
            }
            if ((unsigned)(gcol + 4) < IMG) {
                a1 = *(const float4*)(r1 + gcol + 4);
                b1 = *(const float4*)(r2 + gcol + 4);
            }
        }
    }
}

// h-pass for one 16-row tile: pack 4 planes to bf16, 4 MFMA, write ring slot.
static __device__ __forceinline__ void h_rt(
    float4 a0, float4 a1, float4 b0, float4 b1,
    v8s band, short (*hw)[16][40], int lm, int quad, int slot)
{
    const v4f zacc = {0.f, 0.f, 0.f, 0.f};
    f2 a0l; a0l.x = a0.x; a0l.y = a0.y;   f2 a0h; a0h.x = a0.z; a0h.y = a0.w;
    f2 a1l; a1l.x = a1.x; a1l.y = a1.y;   f2 a1h; a1h.x = a1.z; a1h.y = a1.w;
    f2 b0l; b0l.x = b0.x; b0l.y = b0.y;   f2 b0h; b0h.x = b0.z; b0h.y = b0.w;
    f2 b1l; b1l.x = b1.x; b1l.y = b1.y;   f2 b1h; b1h.x = b1.z; b1h.y = b1.w;

    v8s A[4]; int4 w;
    w.x = cvtpk2(a0l); w.y = cvtpk2(a0h); w.z = cvtpk2(a1l); w.w = cvtpk2(a1h);
    A[0] = __builtin_bit_cast(v8s, w);
    w.x = cvtpk2(b0l); w.y = cvtpk2(b0h); w.z = cvtpk2(b1l); w.w = cvtpk2(b1h);
    A[1] = __builtin_bit_cast(v8s, w);
    w.x = cvtpk2(__builtin_elementwise_fma(a0l, a0l, b0l * b0l));
    w.y = cvtpk2(__builtin_elementwise_fma(a0h, a0h, b0h * b0h));
    w.z = cvtpk2(__builtin_elementwise_fma(a1l, a1l, b1l * b1l));
    w.w = cvtpk2(__builtin_elementwise_fma(a1h, a1h, b1h * b1h));
    A[2] = __builtin_bit_cast(v8s, w);
    w.x = cvtpk2(a0l * b0l); w.y = cvtpk2(a0h * b0h);
    w.z = cvtpk2(a1l * b1l); w.w = cvtpk2(a1h * b1h);
    A[3] = __builtin_bit_cast(v8s, w);

    #pragma unroll
    for (int p = 0; p < 4; ++p) {
        const v4f acc = __builtin_amdgcn_mfma_f32_16x16x32_bf16(A[p], band, zacc, 0, 0, 0);
        // D C-layout: col = lm, rows quad*4 + reg -> ring slot, col-major write.
        int2 w2;
        f2 lo; lo.x = acc[0]; lo.y = acc[1];
        f2 hi; hi.x = acc[2]; hi.y = acc[3];
        w2.x = cvtpk2(lo); w2.y = cvtpk2(hi);
        *(int2*)&hw[p][lm][slot * 16 + quad * 4] = w2;
    }
}

// v-pass for one 16-row output tile + SSIM accumulate.
static __device__ __forceinline__ void v_t2(
    v8s band, short (*hw)[16][40], int lm, int quad, int t2, f2& vsum)
{
    const v4f zacc = {0.f, 0.f, 0.f, 0.f};
    // Ring addressing: window row (t2*16 + quad*8 + j) lives at short
    // ((t2*16 + quad*8) & 31) .. +7 of the column.
    const int bs = (quad * 8 + t2 * 16) & 31;
    v4f acc[4];
    #pragma unroll
    for (int p = 0; p < 4; ++p) {
        const v8s hf = *(const v8s*)&hw[p][lm][bs];
        acc[p] = __builtin_amdgcn_mfma_f32_16x16x32_bf16(band, hf, zacc, 0, 0, 0);
    }
    const f2 C1v = {1e-4f, 1e-4f};        // 0.01^2
    const f2 C2v = {9e-4f, 9e-4f};        // 0.03^2
    const f2 two = {2.f, 2.f};
    #pragma unroll
    for (int h = 0; h < 2; ++h) {
        f2 m1; m1.x = acc[0][2 * h]; m1.y = acc[0][2 * h + 1];
        f2 m2; m2.x = acc[1][2 * h]; m2.y = acc[1][2 * h + 1];
        f2 es; es.x = acc[2][2 * h]; es.y = acc[2][2 * h + 1];
        f2 ex; ex.x = acc[3][2 * h]; ex.y = acc[3][2 * h + 1];
        const f2 m1s = m1 * m1, m2s = m2 * m2, m12 = m1 * m2;
        const f2 sig = es - m1s - m2s;                  // sig1_sq + sig2_sq
        const f2 s12 = ex - m12;
        const f2 num = __builtin_elementwise_fma(two, m12, C1v) *
                       __builtin_elementwise_fma(two, s12, C2v);
        const f2 den = (m1s + m2s + C1v) * (sig + C2v);
        f2 r; r.x = __builtin_amdgcn_rcpf(den.x); r.y = __builtin_amdgcn_rcpf(den.y);
        vsum = __builtin_elementwise_fma(num, r, vsum);
    }
}

__global__ __launch_bounds__(256, 8) void ssim_kernel(
    const float* __restrict__ img1,
    const float* __restrict__ img2,
    const float* __restrict__ win,
    float* __restrict__ partial)
{
    // Per-wave private ring: [wave][plane][col][40 shorts]. 20480 B exactly
    // -> 8 blocks/CU. Shorts 0-31 = two 16-row slots; 32-39 = pad (the final
    // reduce borrows shorts 36-37 of [3][15] as a per-wave float slot).
    __shared__ __align__(16) short hb[4][4][16][40];

    const int tid  = threadIdx.x;
    const int lane = tid & 63;
    const int wave = tid >> 6;
    const int lm   = lane & 15;
    const int quad = lane >> 4;

    const int bx = blockIdx.x, by = blockIdx.y, z = blockIdx.z;
    const int ty0 = by * 32;

    // Band fragment via shuffle: value g[k-i-3], i = lane&15, k = quad*8+j.
    float gl = 0.f;
    if (lane < 11) gl = win[55 + lane] * rsqrtf(win[60]);
    v8s band;
    #pragma unroll
    for (int j = 0; j < 8; ++j) {
        const int t  = quad * 8 + j - lm - 3;
        const int tc = ((unsigned)t > 10u) ? 11 : t;   // lane 11 holds 0
        band[j] = (short)f2bf(__shfl(gl, tc));
    }

    const size_t zoff = (size_t)z * IMG * IMG;
    const float* p1 = img1 + zoff;
    const float* p2 = img2 + zoff;

    // One 16-col tile per wave.
    const int gct = bx * 4 + wave;
    const bool interior = (by > 0) & (by < GY - 1) & (gct > 0) & (gct < 31);
    const int gcol = gct * 16 - 8 + quad * 8;          // 4-aligned
    short (*hw)[16][40] = hb[wave];

    // Loads: 12 float4 per wave (48 VGPR window; fits the 64-VGPR budget).
    float4 a[3][2], b[3][2];
    if (interior) {
        #pragma unroll
        for (int rt = 0; rt < 3; ++rt)
            load_rt<false>(p1, p2, ty0 - 8 + rt * 16 + lm, gcol,
                           a[rt][0], a[rt][1], b[rt][0], b[rt][1]);
    } else {
        #pragma unroll
        for (int rt = 0; rt < 3; ++rt)
            load_rt<true >(p1, p2, ty0 - 8 + rt * 16 + lm, gcol,
                           a[rt][0], a[rt][1], b[rt][0], b[rt][1]);
    }

    f2 vsum = {0.f, 0.f};
    // Ring schedule: rt0->slot0, rt1->slot1, v(rows 0-31), rt2->slot0
    // (overwrites rt0 AFTER its last read; same-wave LDS is in-order and the
    // addresses alias, so program order is preserved), v(rows 16-47).
    h_rt(a[0][0], a[0][1], b[0][0], b[0][1], band, hw, lm, quad, 0);
    h_rt(a[1][0], a[1][1], b[1][0], b[1][1], band, hw, lm, quad, 1);
    v_t2(band, hw, lm, quad, 0, vsum);
    h_rt(a[2][0], a[2][1], b[2][0], b[2][1], band, hw, lm, quad, 0);
    v_t2(band, hw, lm, quad, 1, vsum);

    // ---- wave reduction, then per-BLOCK partial via LDS pad slots ----
    float vs = vsum.x + vsum.y;
    #pragma unroll
    for (int off = 32; off > 0; off >>= 1)
        vs += __shfl_down(vs, off, 64);
    if (lane == 0) *(float*)&hb[wave][3][15][36] = vs;   // pad, wave-private
    __syncthreads();
    if (tid == 0) {
        float t = 0.f;
        #pragma unroll
        for (int w = 0; w < 4; ++w) t += *(const float*)&hb[w][3][15][36];
        partial[(z * GY + by) * GX + bx] = t;
    }
}

__global__ __launch_bounds__(512) void finalize_kernel(
    const float* __restrict__ partial, float* __restrict__ out)
{
    __shared__ float red[8];
    const float4* p4 = (const float4*)partial;
    float s = 0.f;
    #pragma unroll
    for (int i = 0; i < NPART / 4 / 512; ++i) {          // 3 iterations
        const float4 t = p4[i * 512 + threadIdx.x];
        s += (t.x + t.y) + (t.z + t.w);
    }
    #pragma unroll
    for (int off = 32; off > 0; off >>= 1)
        s += __shfl_down(s, off, 64);
    if ((threadIdx.x & 63) == 0) red[threadIdx.x >> 6] = s;
    __syncthreads();
    if (threadIdx.x == 0) {
        float t = 0.f;
        #pragma unroll
        for (int i = 0; i < 8; ++i) t += red[i];
        out[0] = 1.0f - t / (float)NPIX;
    }
}

extern "C" void kernel_launch(void* const* d_in, const int* in_sizes, int n_in,
                              void* d_out, int out_size, void* d_ws, size_t ws_size,
                              hipStream_t stream) {
    const float* img1 = (const float*)d_in[0];
    const float* img2 = (const float*)d_in[1];
    const float* win  = (const float*)d_in[2];
    float* partialb = (float*)d_ws;  // NPART floats = 24 KB; fully rewritten each call

    dim3 grid(GX, GY, 48);
    ssim_kernel<<<grid, dim3(256), 0, stream>>>(img1, img2, win, partialb);
    finalize_kernel<<<1, dim3(512), 0, stream>>>(partialb, (float*)d_out);
}

// Round 2
// 143.763 us; speedup vs baseline: 1.1839x; 1.1839x over previous
//
#include <hip/hip_runtime.h>

// SSIM fused, v11: v10 occupancy structure with the SPILL fixed.
// v10 post-mortem: __launch_bounds__(256,8) -> compiler allocated 32 VGPRs and
// spilled ~4 float4/thread of the upfront load window to scratch
// (WRITE_SIZE 0.12 -> 92.4 MB, FETCH +30 MB); dur 53 -> 77 us despite
// occupancy 32 -> 73%. v11:
//   - __launch_bounds__(256, 6): ~84-VGPR cap, 6 blocks/CU (75% static
//     occupancy; LDS 20480 B would allow 8, VGPR binds at 6). Still 2.4x v9's
//     waves/CU.
//   - Load schedule trimmed to ~50 VGPR peak: issue rt0+rt1 (8 float4),
//     h0->slot0, h1->slot1, issue rt2, v-pass0 (rt2 latency hides under it),
//     h2->slot0, v-pass1. No 12-float4 window ever live at once.
//   - Everything else identical to v10 (harness-verified math): ring-buffered
//     H planes (2 slots, pitch 40 shorts), one 16-col tile per wave,
//     per-block partial via LDS pad slot, band[j]=g[quad*8+j-lm-3] via __shfl.

#define IMG 512
#define NPIX (16LL * 3 * 512 * 512)
#define GX 8                  /* 512 / (16 cols * 4 waves) */
#define GY 16                 /* 512 / 32 rows */
#define NBLK (GX * GY * 48)   /* 6144 blocks */
#define NPART NBLK            /* one float per block: 24 KB */

typedef short v8s __attribute__((ext_vector_type(8)));   // 8 x bf16 (4 VGPRs)
typedef float v4f __attribute__((ext_vector_type(4)));   // MFMA accumulator
typedef __bf16 bf2 __attribute__((ext_vector_type(2)));
typedef float f2  __attribute__((ext_vector_type(2)));

static __device__ __forceinline__ int cvtpk2(f2 v) {     // v_cvt_pk_bf16_f32
    bf2 r = __builtin_convertvector(v, bf2);
    return __builtin_bit_cast(int, r);
}
static __device__ __forceinline__ unsigned f2bf(float f) {
    unsigned u = __float_as_uint(f);
    return (u + 0x7FFFu + ((u >> 16) & 1u)) >> 16;
}

// One row-tile of raw loads: 4 float4 (row grow, cols gcol..gcol+7, 2 imgs).
template <bool EDGE>
static __device__ __forceinline__ void load_rt(
    const float* __restrict__ p1, const float* __restrict__ p2,
    int grow, int gcol,
    float4& a0, float4& a1, float4& b0, float4& b1)
{
    if (!EDGE) {
        const float* r1 = p1 + (size_t)grow * IMG + gcol;
        const float* r2 = p2 + (size_t)grow * IMG + gcol;
        a0 = *(const float4*)r1;       a1 = *(const float4*)(r1 + 4);
        b0 = *(const float4*)r2;       b1 = *(const float4*)(r2 + 4);
    } else {
        float4 z4; z4.x = z4.y = z4.z = z4.w = 0.f;
        a0 = a1 = b0 = b1 = z4;
        if ((unsigned)grow < IMG) {
            const float* r1 = p1 + (size_t)grow * IMG;
            const float* r2 = p2 + (size_t)grow * IMG;
            if ((unsigned)gcol < IMG) {
                a0 = *(const float4*)(r1 + gcol);
                b0 = *(const float4*)(r2 + gcol);
            }
            if ((unsigned)(gcol + 4) < IMG) {
                a1 = *(const float4*)(r1 + gcol + 4);
                b1 = *(const float4*)(r2 + gcol + 4);
            }
        }
    }
}

// h-pass for one 16-row tile: pack 4 planes to bf16, 4 MFMA, write ring slot.
static __device__ __forceinline__ void h_rt(
    float4 a0, float4 a1, float4 b0, float4 b1,
    v8s band, short (*hw)[16][40], int lm, int quad, int slot)
{
    const v4f zacc = {0.f, 0.f, 0.f, 0.f};
    f2 a0l; a0l.x = a0.x; a0l.y = a0.y;   f2 a0h; a0h.x = a0.z; a0h.y = a0.w;
    f2 a1l; a1l.x = a1.x; a1l.y = a1.y;   f2 a1h; a1h.x = a1.z; a1h.y = a1.w;
    f2 b0l; b0l.x = b0.x; b0l.y = b0.y;   f2 b0h; b0h.x = b0.z; b0h.y = b0.w;
    f2 b1l; b1l.x = b1.x; b1l.y = b1.y;   f2 b1h; b1h.x = b1.z; b1h.y = b1.w;

    v8s A[4]; int4 w;
    w.x = cvtpk2(a0l); w.y = cvtpk2(a0h); w.z = cvtpk2(a1l); w.w = cvtpk2(a1h);
    A[0] = __builtin_bit_cast(v8s, w);
    w.x = cvtpk2(b0l); w.y = cvtpk2(b0h); w.z = cvtpk2(b1l); w.w = cvtpk2(b1h);
    A[1] = __builtin_bit_cast(v8s, w);
    w.x = cvtpk2(__builtin_elementwise_fma(a0l, a0l, b0l * b0l));
    w.y = cvtpk2(__builtin_elementwise_fma(a0h, a0h, b0h * b0h));
    w.z = cvtpk2(__builtin_elementwise_fma(a1l, a1l, b1l * b1l));
    w.w = cvtpk2(__builtin_elementwise_fma(a1h, a1h, b1h * b1h));
    A[2] = __builtin_bit_cast(v8s, w);
    w.x = cvtpk2(a0l * b0l); w.y = cvtpk2(a0h * b0h);
    w.z = cvtpk2(a1l * b1l); w.w = cvtpk2(a1h * b1h);
    A[3] = __builtin_bit_cast(v8s, w);

    #pragma unroll
    for (int p = 0; p < 4; ++p) {
        const v4f acc = __builtin_amdgcn_mfma_f32_16x16x32_bf16(A[p], band, zacc, 0, 0, 0);
        // D C-layout: col = lm, rows quad*4 + reg -> ring slot, col-major write.
        int2 w2;
        f2 lo; lo.x = acc[0]; lo.y = acc[1];
        f2 hi; hi.x = acc[2]; hi.y = acc[3];
        w2.x = cvtpk2(lo); w2.y = cvtpk2(hi);
        *(int2*)&hw[p][lm][slot * 16 + quad * 4] = w2;
    }
}

// v-pass for one 16-row output tile + SSIM accumulate.
static __device__ __forceinline__ void v_t2(
    v8s band, short (*hw)[16][40], int lm, int quad, int t2, f2& vsum)
{
    const v4f zacc = {0.f, 0.f, 0.f, 0.f};
    // Ring addressing: window row (t2*16 + quad*8 + j) lives at short
    // ((t2*16 + quad*8) & 31) .. +7 of the column.
    const int bs = (quad * 8 + t2 * 16) & 31;
    v4f acc[4];
    #pragma unroll
    for (int p = 0; p < 4; ++p) {
        const v8s hf = *(const v8s*)&hw[p][lm][bs];
        acc[p] = __builtin_amdgcn_mfma_f32_16x16x32_bf16(band, hf, zacc, 0, 0, 0);
    }
    const f2 C1v = {1e-4f, 1e-4f};        // 0.01^2
    const f2 C2v = {9e-4f, 9e-4f};        // 0.03^2
    const f2 two = {2.f, 2.f};
    #pragma unroll
    for (int h = 0; h < 2; ++h) {
        f2 m1; m1.x = acc[0][2 * h]; m1.y = acc[0][2 * h + 1];
        f2 m2; m2.x = acc[1][2 * h]; m2.y = acc[1][2 * h + 1];
        f2 es; es.x = acc[2][2 * h]; es.y = acc[2][2 * h + 1];
        f2 ex; ex.x = acc[3][2 * h]; ex.y = acc[3][2 * h + 1];
        const f2 m1s = m1 * m1, m2s = m2 * m2, m12 = m1 * m2;
        const f2 sig = es - m1s - m2s;                  // sig1_sq + sig2_sq
        const f2 s12 = ex - m12;
        const f2 num = __builtin_elementwise_fma(two, m12, C1v) *
                       __builtin_elementwise_fma(two, s12, C2v);
        const f2 den = (m1s + m2s + C1v) * (sig + C2v);
        f2 r; r.x = __builtin_amdgcn_rcpf(den.x); r.y = __builtin_amdgcn_rcpf(den.y);
        vsum = __builtin_elementwise_fma(num, r, vsum);
    }
}

__global__ __launch_bounds__(256, 6) void ssim_kernel(
    const float* __restrict__ img1,
    const float* __restrict__ img2,
    const float* __restrict__ win,
    float* __restrict__ partial)
{
    // Per-wave private ring: [wave][plane][col][40 shorts]. 20480 B.
    // Shorts 0-31 = two 16-row slots; 32-39 = pad (final reduce borrows
    // shorts 36-37 of [3][15] as a per-wave float slot).
    __shared__ __align__(16) short hb[4][4][16][40];

    const int tid  = threadIdx.x;
    const int lane = tid & 63;
    const int wave = tid >> 6;
    const int lm   = lane & 15;
    const int quad = lane >> 4;

    const int bx = blockIdx.x, by = blockIdx.y, z = blockIdx.z;
    const int ty0 = by * 32;

    // Band fragment via shuffle: value g[k-i-3], i = lane&15, k = quad*8+j.
    float gl = 0.f;
    if (lane < 11) gl = win[55 + lane] * rsqrtf(win[60]);
    v8s band;
    #pragma unroll
    for (int j = 0; j < 8; ++j) {
        const int t  = quad * 8 + j - lm - 3;
        const int tc = ((unsigned)t > 10u) ? 11 : t;   // lane 11 holds 0
        band[j] = (short)f2bf(__shfl(gl, tc));
    }

    const size_t zoff = (size_t)z * IMG * IMG;
    const float* p1 = img1 + zoff;
    const float* p2 = img2 + zoff;

    // One 16-col tile per wave.
    const int gct = bx * 4 + wave;
    const bool interior = (by > 0) & (by < GY - 1) & (gct > 0) & (gct < 31);
    const int gcol = gct * 16 - 8 + quad * 8;          // 4-aligned
    short (*hw)[16][40] = hb[wave];

    f2 vsum = {0.f, 0.f};
    // Schedule (peak ~50 VGPR live, vs v10's 12-float4 window that spilled):
    //   issue rt0+rt1 -> h0(slot0), h1(slot1) -> issue rt2 -> v0
    //   (rt2 latency hides under v0) -> h2(slot0) -> v1.
    // Slot0 overwrite happens AFTER v0's last read of it; same-wave LDS is
    // in-order and the addresses alias, so program order is preserved.
    {
        float4 a0[2], b0[2], a1[2], b1[2], a2[2], b2[2];
        if (interior) {
            load_rt<false>(p1, p2, ty0 - 8 + 0 * 16 + lm, gcol, a0[0], a0[1], b0[0], b0[1]);
            load_rt<false>(p1, p2, ty0 - 8 + 1 * 16 + lm, gcol, a1[0], a1[1], b1[0], b1[1]);
        } else {
            load_rt<true >(p1, p2, ty0 - 8 + 0 * 16 + lm, gcol, a0[0], a0[1], b0[0], b0[1]);
            load_rt<true >(p1, p2, ty0 - 8 + 1 * 16 + lm, gcol, a1[0], a1[1], b1[0], b1[1]);
        }
        h_rt(a0[0], a0[1], b0[0], b0[1], band, hw, lm, quad, 0);
        h_rt(a1[0], a1[1], b1[0], b1[1], band, hw, lm, quad, 1);
        if (interior)
            load_rt<false>(p1, p2, ty0 - 8 + 2 * 16 + lm, gcol, a2[0], a2[1], b2[0], b2[1]);
        else
            load_rt<true >(p1, p2, ty0 - 8 + 2 * 16 + lm, gcol, a2[0], a2[1], b2[0], b2[1]);
        v_t2(band, hw, lm, quad, 0, vsum);
        h_rt(a2[0], a2[1], b2[0], b2[1], band, hw, lm, quad, 0);
        v_t2(band, hw, lm, quad, 1, vsum);
    }

    // ---- wave reduction, then per-BLOCK partial via LDS pad slots ----
    float vs = vsum.x + vsum.y;
    #pragma unroll
    for (int off = 32; off > 0; off >>= 1)
        vs += __shfl_down(vs, off, 64);
    if (lane == 0) *(float*)&hb[wave][3][15][36] = vs;   // pad, wave-private
    __syncthreads();
    if (tid == 0) {
        float t = 0.f;
        #pragma unroll
        for (int w = 0; w < 4; ++w) t += *(const float*)&hb[w][3][15][36];
        partial[(z * GY + by) * GX + bx] = t;
    }
}

__global__ __launch_bounds__(512) void finalize_kernel(
    const float* __restrict__ partial, float* __restrict__ out)
{
    __shared__ float red[8];
    const float4* p4 = (const float4*)partial;
    float s = 0.f;
    #pragma unroll
    for (int i = 0; i < NPART / 4 / 512; ++i) {          // 3 iterations
        const float4 t = p4[i * 512 + threadIdx.x];
        s += (t.x + t.y) + (t.z + t.w);
    }
    #pragma unroll
    for (int off = 32; off > 0; off >>= 1)
        s += __shfl_down(s, off, 64);
    if ((threadIdx.x & 63) == 0) red[threadIdx.x >> 6] = s;
    __syncthreads();
    if (threadIdx.x == 0) {
        float t = 0.f;
        #pragma unroll
        for (int i = 0; i < 8; ++i) t += red[i];
        out[0] = 1.0f - t / (float)NPIX;
    }
}

extern "C" void kernel_launch(void* const* d_in, const int* in_sizes, int n_in,
                              void* d_out, int out_size, void* d_ws, size_t ws_size,
                              hipStream_t stream) {
    const float* img1 = (const float*)d_in[0];
    const float* img2 = (const float*)d_in[1];
    const float* win  = (const float*)d_in[2];
    float* partialb = (float*)d_ws;  // NPART floats = 24 KB; fully rewritten each call

    dim3 grid(GX, GY, 48);
    ssim_kernel<<<grid, dim3(256), 0, stream>>>(img1, img2, win, partialb);
    finalize_kernel<<<1, dim3(512), 0, stream>>>(partialb, (float*)d_out);
}